// Round 4
// baseline (256.365 us; speedup 1.0000x reference)
//
#include <hip/hip_runtime.h>
#include <math.h>

// Problem constants
#define B  16384
#define K  1024
#define D  512
#define EPS 1e-12f

// softmax in base-2: log2(e^{(s+g)/tau}) = SM_C1*s - 10*log2(-log2(u)) + SM_C2
//   tau = 0.1 ; SM_C1 = 10*log2(e) ; SM_C2 = -10*log2(ln 2)
#define SM_C1 14.426950408889634f
#define SM_C2 5.287663729448977f

typedef unsigned short ushort_t;

// raw gfx950 transcendentals: v_log_f32 = log2(x), v_exp_f32 = 2^x
#define LOG2F(x) __builtin_amdgcn_logf(x)
#define EXP2F(x) __builtin_amdgcn_exp2f(x)

// d_out layout (floats): [0, B*D) pt ; [B*D, B*D+K*D) p ; then sim_loss, div_loss
#define OUT_PT   0
#define OUT_P    (B*D)
#define OUT_SIM  (B*D + K*D)
#define OUT_DIV  (B*D + K*D + 1)

// ws layout (floats):
//  [1024,1536)      simsm per-block dot partials (512)
//  [32768, +B*K/2)  Eh f16 [B][1024] (written by simsm, read by gemm2)
//  then Ph   [1024][512] f16 (1 MB)
//  then PTh  [512][1024] f16 (1 MB)
//  then DIAGP[256], COLP[256][512]  (norm_p per-block partials, no atomics)
#define WS_RED   1024
#define WS_SIM   32768
#define WS_PH    (WS_SIM + (B*K)/2)
#define WS_PTH   (WS_PH + (K*D)/2)
#define WS_DIAGP (WS_PTH + (K*D)/2)
#define WS_COLP  (WS_DIAGP + 256)

// Xh f16 [16384][512] (16 MB) lives in d_out's pt region, consumed by simsm
// before gemm2 overwrites pt.

typedef _Float16 half8 __attribute__((ext_vector_type(8)));
typedef float f32x4 __attribute__((ext_vector_type(4)));

__device__ __forceinline__ float wave_reduce_sum(float v) {
    #pragma unroll
    for (int off = 32; off >= 1; off >>= 1) v += __shfl_down(v, off);
    return v;
}

__device__ __forceinline__ ushort_t f2h(float f) {
    _Float16 h = (_Float16)f;
    return __builtin_bit_cast(ushort_t, h);
}
__device__ __forceinline__ float h2f(ushort_t u) {
    return (float)__builtin_bit_cast(_Float16, u);
}

__device__ __forceinline__ void async16(const void* g, void* l) {
    __builtin_amdgcn_global_load_lds(
        (const __attribute__((address_space(1))) unsigned int*)g,
        (__attribute__((address_space(3))) unsigned int*)l, 16, 0, 0);
}

// Normalize prototypes (one wave per row, 4 rows/block). Fused outputs:
//  - phat fp32 -> d_out (output 1)
//  - Ph f16 [1024][512]
//  - per-block colsum partial [512] -> ws[WS_COLP + blk*512]
//  - per-block diag partial -> ws[WS_DIAGP + blk]
__global__ __launch_bounds__(256) void norm_p_kernel(const float* __restrict__ proto,
                                                     float* __restrict__ out,
                                                     float* __restrict__ ws,
                                                     ushort_t* __restrict__ Ph) {
    __shared__ float cs[4][512];
    __shared__ float red[4];
    int tid = threadIdx.x, wid = tid >> 6, lane = tid & 63;
    int row = blockIdx.x * 4 + wid;
    const float4* pr = (const float4*)(proto + (size_t)row * D);
    float4 a = pr[lane * 2], b = pr[lane * 2 + 1];
    float ss = a.x*a.x + a.y*a.y + a.z*a.z + a.w*a.w
             + b.x*b.x + b.y*b.y + b.z*b.z + b.w*b.w;
    ss = wave_reduce_sum(ss);
    ss = __shfl(ss, 0);
    float inv = 1.0f / fmaxf(sqrtf(ss), EPS);
    float4 na = make_float4(a.x*inv, a.y*inv, a.z*inv, a.w*inv);
    float4 nb = make_float4(b.x*inv, b.y*inv, b.z*inv, b.w*inv);
    float4* po = (float4*)(out + OUT_P + (size_t)row * D);
    po[lane * 2]     = na;
    po[lane * 2 + 1] = nb;
    ushort4* ph = (ushort4*)(Ph + (size_t)row * D);
    ph[lane * 2]     = make_ushort4(f2h(na.x), f2h(na.y), f2h(na.z), f2h(na.w));
    ph[lane * 2 + 1] = make_ushort4(f2h(nb.x), f2h(nb.y), f2h(nb.z), f2h(nb.w));
    *(float4*)(&cs[wid][lane * 8])     = na;
    *(float4*)(&cs[wid][lane * 8 + 4]) = nb;
    if (lane == 0) red[wid] = ss * inv * inv;
    __syncthreads();
    float c0 = cs[0][tid] + cs[1][tid] + cs[2][tid] + cs[3][tid];
    float c1 = cs[0][tid + 256] + cs[1][tid + 256] + cs[2][tid + 256] + cs[3][tid + 256];
    ws[WS_COLP + (size_t)blockIdx.x * 512 + tid]       = c0;
    ws[WS_COLP + (size_t)blockIdx.x * 512 + tid + 256] = c1;
    if (tid == 0) ws[WS_DIAGP + blockIdx.x] = red[0] + red[1] + red[2] + red[3];
}

// PTh [512][1024] f16: transpose of phat
__global__ __launch_bounds__(256) void ptcvt_kernel(const float* __restrict__ out,
                                                    ushort_t* __restrict__ PT) {
    __shared__ float tile[64][65];
    int k0 = blockIdx.x * 64, d0 = blockIdx.y * 64;
    int tid = threadIdx.x;
    const float* phat = out + OUT_P;
    #pragma unroll
    for (int i = tid; i < 64 * 64; i += 256) {
        int kk = i >> 6, dd = i & 63;
        tile[dd][kk] = phat[(size_t)(k0 + kk) * D + d0 + dd];
    }
    __syncthreads();
    #pragma unroll
    for (int i = tid; i < 64 * 64; i += 256) {
        int dd = i >> 6, kk = i & 63;
        PT[(size_t)(d0 + dd) * K + k0 + kk] = f2h(tile[dd][kk]);
    }
}

// Fused x row-norm + f16 convert: Xh [16384][512] in out's pt region.
__global__ __launch_bounds__(256) void xcvt_kernel(const float* __restrict__ x,
                                                   ushort_t* __restrict__ Xh) {
    int wid = threadIdx.x >> 6, lane = threadIdx.x & 63;
    int row = blockIdx.x * 4 + wid;
    const float4* xr = (const float4*)(x + (size_t)row * D);
    float4 a = xr[lane * 2], b = xr[lane * 2 + 1];
    float ss = a.x*a.x + a.y*a.y + a.z*a.z + a.w*a.w
             + b.x*b.x + b.y*b.y + b.z*b.z + b.w*b.w;
    ss = wave_reduce_sum(ss);
    ss = __shfl(ss, 0);
    float inv = 1.0f / fmaxf(sqrtf(ss), EPS);
    ushort4 h0 = make_ushort4(f2h(a.x*inv), f2h(a.y*inv), f2h(a.z*inv), f2h(a.w*inv));
    ushort4 h1 = make_ushort4(f2h(b.x*inv), f2h(b.y*inv), f2h(b.z*inv), f2h(b.w*inv));
    ushort4* xo = (ushort4*)(Xh + (size_t)row * D);
    xo[lane * 2]     = h0;
    xo[lane * 2 + 1] = h1;
}

// ---------------------------------------------------------------------------
// Fused sim-GEMM + gumbel-softmax, v3: NO B-staging (Ph is 1 MB -> L2-fits;
// stage-only-what-doesn't-cache-fit). Block: 32 X-rows x ALL 1024 proto cols,
// 16 waves, each wave owns a 32x64 column slab (acc = 32 f32/lane).
// A-slab (32x512 f16 = 32 KB) staged to LDS ONCE (XOR-swizzled, 2-way banks);
// B fragments loaded DIRECTLY global->VGPR (per-lane 16 B dwordx4, L2-hit) --
// no barriers in the K-loop, 16 independent waves, ILP from full unroll.
// Gumbel loads issued mid-K-loop so HBM latency hides under the 2nd half.
// Softmax in-register as before; Et (64 KB) overlays the A-slab after
// barriers. LDS ~70 KB.
// ---------------------------------------------------------------------------
__global__ __launch_bounds__(1024) void simsm_kernel(const ushort_t* __restrict__ Xh,
                                                     const ushort_t* __restrict__ Ph,
                                                     const float* __restrict__ gum,
                                                     ushort_t* __restrict__ Eh,
                                                     float* __restrict__ ws) {
    __shared__ __align__(16) ushort_t EtBuf[32 * K];   // 64 KB; first 32 KB doubles as A-slab
    __shared__ float wredM[16][32];
    __shared__ float wredS[16][32];
    __shared__ float wredD[16][32];
    __shared__ float rowM[32];
    __shared__ float rowInv[32];
    __shared__ float rowDotA[32];

    int tid = threadIdx.x;
    int wid = tid >> 6, lane = tid & 63;
    int quad = lane >> 4, l16 = lane & 15;
    int wn = wid * 64;               // this wave's proto-column base
    int bm0 = blockIdx.x * 32;       // this block's X-row base

    char* AsL = (char*)&EtBuf[0];    // A-slab: 32 rows x 1024 B, XOR-16B swizzle

    // ---- stage A-slab once: 2048 x 16B chunks, swizzled ds_write ----
    #pragma unroll
    for (int c = tid; c < 2048; c += 1024) {
        int row = c >> 6, k16 = c & 63;
        uint4 v = *(const uint4*)(Xh + (size_t)(bm0 + row) * 512 + k16 * 8);
        *(uint4*)(AsL + row * 1024 + ((k16 * 16) ^ ((row & 7) << 4))) = v;
    }
    __syncthreads();

    // per-lane B pointers: row wn + 16j + l16, k-offset quad*8
    const ushort_t* bp0 = Ph + (size_t)(wn + l16) * 512 + quad * 8;

    f32x4 acc[2][4] = {};

    #define SIMSM_STEP(kc) do {                                                   \
        half8 a0, a1;                                                             \
        {                                                                         \
            int r0 = l16;                                                         \
            a0 = *(const half8*)(AsL + r0 * 1024 +                                \
                                 (((kc) * 2 + quad * 16) ^ ((r0 & 7) << 4)));     \
            int r1 = 16 + l16;                                                    \
            a1 = *(const half8*)(AsL + r1 * 1024 +                                \
                                 (((kc) * 2 + quad * 16) ^ ((r1 & 7) << 4)));     \
        }                                                                         \
        half8 b0 = *(const half8*)(bp0 + (kc));                                   \
        half8 b1 = *(const half8*)(bp0 + 16 * 512 + (kc));                        \
        half8 b2 = *(const half8*)(bp0 + 32 * 512 + (kc));                        \
        half8 b3 = *(const half8*)(bp0 + 48 * 512 + (kc));                        \
        acc[0][0] = __builtin_amdgcn_mfma_f32_16x16x32_f16(a0, b0, acc[0][0], 0, 0, 0); \
        acc[1][0] = __builtin_amdgcn_mfma_f32_16x16x32_f16(a1, b0, acc[1][0], 0, 0, 0); \
        acc[0][1] = __builtin_amdgcn_mfma_f32_16x16x32_f16(a0, b1, acc[0][1], 0, 0, 0); \
        acc[1][1] = __builtin_amdgcn_mfma_f32_16x16x32_f16(a1, b1, acc[1][1], 0, 0, 0); \
        acc[0][2] = __builtin_amdgcn_mfma_f32_16x16x32_f16(a0, b2, acc[0][2], 0, 0, 0); \
        acc[1][2] = __builtin_amdgcn_mfma_f32_16x16x32_f16(a1, b2, acc[1][2], 0, 0, 0); \
        acc[0][3] = __builtin_amdgcn_mfma_f32_16x16x32_f16(a0, b3, acc[0][3], 0, 0, 0); \
        acc[1][3] = __builtin_amdgcn_mfma_f32_16x16x32_f16(a1, b3, acc[1][3], 0, 0, 0); \
    } while (0)

    // first half of K
    #pragma unroll
    for (int kc = 0; kc < 256; kc += 32) SIMSM_STEP(kc);

    // gumbel prefetch (32 dword loads) -- HBM latency hides under 2nd half
    float gu[2][4][4];
    #pragma unroll
    for (int i = 0; i < 2; ++i)
        #pragma unroll
        for (int j = 0; j < 4; ++j)
            #pragma unroll
            for (int r = 0; r < 4; ++r)
                gu[i][j][r] = gum[(size_t)(bm0 + 16*i + 4*quad + r) * K + wn + 16*j + l16];

    // second half of K
    #pragma unroll
    for (int kc = 256; kc < 512; kc += 32) SIMSM_STEP(kc);
    #undef SIMSM_STEP

    // ---- softmax: lane's rows are 16i + 4*quad + r, cols wn + 16j + l16 ----
    float zz[2][4][4];
    #pragma unroll
    for (int i = 0; i < 2; ++i)
        #pragma unroll
        for (int j = 0; j < 4; ++j)
            #pragma unroll
            for (int r = 0; r < 4; ++r) {
                float t = -LOG2F(gu[i][j][r]);     // t > 0
                float l2t = LOG2F(t);
                zz[i][j][r] = SM_C1 * acc[i][j][r] - 10.0f * l2t + SM_C2;
            }

    // wave-local row max over this wave's 64 cols
    float mx[2][4];
    #pragma unroll
    for (int i = 0; i < 2; ++i)
        #pragma unroll
        for (int r = 0; r < 4; ++r) {
            float m = fmaxf(fmaxf(zz[i][0][r], zz[i][1][r]),
                            fmaxf(zz[i][2][r], zz[i][3][r]));
            m = fmaxf(m, __shfl_xor(m, 1));
            m = fmaxf(m, __shfl_xor(m, 2));
            m = fmaxf(m, __shfl_xor(m, 4));
            m = fmaxf(m, __shfl_xor(m, 8));
            mx[i][r] = m;
        }
    if (l16 == 0) {
        #pragma unroll
        for (int i = 0; i < 2; ++i)
            #pragma unroll
            for (int r = 0; r < 4; ++r)
                wredM[wid][16*i + 4*quad + r] = mx[i][r];
    }
    __syncthreads();
    if (tid < 32) {
        float m = wredM[0][tid];
        #pragma unroll
        for (int w = 1; w < 16; ++w) m = fmaxf(m, wredM[w][tid]);
        rowM[tid] = m;
    }
    __syncthreads();

    // e = exp2(z2 - m); per-row sum and dot (e * s), cross-wave via LDS
    #pragma unroll
    for (int i = 0; i < 2; ++i)
        #pragma unroll
        for (int r = 0; r < 4; ++r) {
            float m = rowM[16*i + 4*quad + r];
            float eacc = 0.0f, dacc = 0.0f;
            #pragma unroll
            for (int j = 0; j < 4; ++j) {
                float e = EXP2F(zz[i][j][r] - m);
                zz[i][j][r] = e;
                eacc += e;
                dacc += e * acc[i][j][r];
            }
            eacc += __shfl_xor(eacc, 1); dacc += __shfl_xor(dacc, 1);
            eacc += __shfl_xor(eacc, 2); dacc += __shfl_xor(dacc, 2);
            eacc += __shfl_xor(eacc, 4); dacc += __shfl_xor(dacc, 4);
            eacc += __shfl_xor(eacc, 8); dacc += __shfl_xor(dacc, 8);
            if (l16 == 0) {
                wredS[wid][16*i + 4*quad + r] = eacc;
                wredD[wid][16*i + 4*quad + r] = dacc;
            }
        }
    __syncthreads();
    if (tid < 32) {
        float s = 0.0f, dd = 0.0f;
        #pragma unroll
        for (int w = 0; w < 16; ++w) { s += wredS[w][tid]; dd += wredD[w][tid]; }
        rowInv[tid] = 1.0f / s;
        rowDotA[tid] = dd / s;
    }
    __syncthreads();   // also: all A-slab reads done before Et overlays it

    // normalized E -> LDS transpose buffer, then coalesced f16 store
    ushort_t* Et = &EtBuf[0];
    #pragma unroll
    for (int i = 0; i < 2; ++i)
        #pragma unroll
        for (int r = 0; r < 4; ++r) {
            int row = 16*i + 4*quad + r;
            float inv = rowInv[row];
            #pragma unroll
            for (int j = 0; j < 4; ++j)
                Et[row * K + wn + 16*j + l16] = f2h(zz[i][j][r] * inv);
        }
    if (tid == 0) {
        float dsum = 0.0f;
        #pragma unroll
        for (int k = 0; k < 32; ++k) dsum += rowDotA[k];
        ws[WS_RED + blockIdx.x] = dsum;
    }
    __syncthreads();
    {
        int row = tid >> 5, seg = tid & 31;   // 64 B per thread
        const uint4* src = (const uint4*)(Et + row * K + seg * 32);
        uint4* dst = (uint4*)(Eh + (size_t)(bm0 + row) * K + seg * 32);
        dst[0] = src[0]; dst[1] = src[1]; dst[2] = src[2]; dst[3] = src[3];
    }
}

// f16 bt-GEMM (m97 recipe), used for pt = Eh · PTh^T. 128x128 tile, 4 waves,
// BK=64 via two 32-k panels, global_load_lds width-16 staging.
template<int LDA, int LDB, int LDC, int KK, bool F16C>
__global__ __launch_bounds__(256) void gemm_bt2(const ushort_t* __restrict__ A,
                                                const ushort_t* __restrict__ Bm,
                                                void* __restrict__ Cv) {
    __shared__ __align__(16) ushort_t As[2 * 128 * 32];
    __shared__ __align__(16) ushort_t Bs[2 * 128 * 32];
    int tid = threadIdx.x;
    int wid = tid >> 6, lane = tid & 63;
    int quad = lane >> 4, l16 = lane & 15;
    int wm = (wid & 1) * 64, wn = (wid >> 1) * 64;
    int bn0 = blockIdx.x * 128, bm0 = blockIdx.y * 128;
    int ldrow = lane >> 2;
    int lcol  = (lane & 3) * 8;

    f32x4 acc[4][4] = {};

    ushort_t* AsD[2][2] = {
        { As + (wid * 16) * 32,        As + (64 + wid * 16) * 32 },
        { As + 4096 + (wid * 16) * 32, As + 4096 + (64 + wid * 16) * 32 } };
    ushort_t* BsD[2][2] = {
        { Bs + (wid * 16) * 32,        Bs + (64 + wid * 16) * 32 },
        { Bs + 4096 + (wid * 16) * 32, Bs + 4096 + (64 + wid * 16) * 32 } };

    const ushort_t* Ab = A + (size_t)(bm0 + wid * 16 + ldrow) * LDA + lcol;
    const ushort_t* Bb = Bm + (size_t)(bn0 + wid * 16 + ldrow) * LDB + lcol;

    for (int kc = 0; kc < KK; kc += 64) {
        async16(Ab + kc,                       AsD[0][0]);
        async16(Ab + kc + (size_t)64 * LDA,    AsD[0][1]);
        async16(Ab + kc + 32,                  AsD[1][0]);
        async16(Ab + kc + 32 + (size_t)64*LDA, AsD[1][1]);
        async16(Bb + kc,                       BsD[0][0]);
        async16(Bb + kc + (size_t)64 * LDB,    BsD[0][1]);
        async16(Bb + kc + 32,                  BsD[1][0]);
        async16(Bb + kc + 32 + (size_t)64*LDB, BsD[1][1]);
        __syncthreads();
        #pragma unroll
        for (int p = 0; p < 2; ++p) {
            half8 af[4], bg[4];
            #pragma unroll
            for (int i = 0; i < 4; ++i)
                af[i] = *(const half8*)(As + p * 4096 + (wm + 16 * i + l16) * 32 + quad * 8);
            #pragma unroll
            for (int j = 0; j < 4; ++j)
                bg[j] = *(const half8*)(Bs + p * 4096 + (wn + 16 * j + l16) * 32 + quad * 8);
            #pragma unroll
            for (int i = 0; i < 4; ++i)
                #pragma unroll
                for (int j = 0; j < 4; ++j)
                    acc[i][j] = __builtin_amdgcn_mfma_f32_16x16x32_f16(af[i], bg[j], acc[i][j], 0, 0, 0);
        }
        __syncthreads();
    }
    #pragma unroll
    for (int i = 0; i < 4; ++i) {
        #pragma unroll
        for (int j = 0; j < 4; ++j) {
            #pragma unroll
            for (int r = 0; r < 4; ++r) {
                int row = bm0 + wm + 16 * i + quad * 4 + r;
                int col = bn0 + wn + 16 * j + l16;
                if (F16C)
                    ((ushort_t*)Cv)[(size_t)row * LDC + col] = f2h(acc[i][j][r]);
                else
                    ((float*)Cv)[(size_t)row * LDC + col] = acc[i][j][r];
            }
        }
    }
}

// Final reduction: simsm dot partials (512), diag partials (256),
// colsum partials (256 x 512 -> ||colsum||^2).
__global__ __launch_bounds__(256) void finalize_kernel(float* __restrict__ out,
                                                       const float* __restrict__ ws) {
    int tid = threadIdx.x, wid = tid >> 6, lane = tid & 63;
    float vdot = ws[WS_RED + tid] + ws[WS_RED + tid + 256];
    float diag = ws[WS_DIAGP + tid];
    float c0 = 0.0f, c1 = 0.0f;
    for (int b2 = 0; b2 < 256; ++b2) {
        c0 += ws[WS_COLP + (size_t)b2 * 512 + tid];
        c1 += ws[WS_COLP + (size_t)b2 * 512 + tid + 256];
    }
    float vssq = c0 * c0 + c1 * c1;
    vdot = wave_reduce_sum(vdot);
    vssq = wave_reduce_sum(vssq);
    diag = wave_reduce_sum(diag);
    __shared__ float rd[4], rs[4], rg[4];
    if (lane == 0) { rd[wid] = vdot; rs[wid] = vssq; rg[wid] = diag; }
    __syncthreads();
    if (tid == 0) {
        float dot = rd[0] + rd[1] + rd[2] + rd[3];
        float ssq = rs[0] + rs[1] + rs[2] + rs[3];
        float dg  = rg[0] + rg[1] + rg[2] + rg[3];
        out[OUT_SIM] = 1.0f - dot * (1.0f / (float)B);
        out[OUT_DIV] = ssq - dg;
    }
}

extern "C" void kernel_launch(void* const* d_in, const int* in_sizes, int n_in,
                              void* d_out, int out_size, void* d_ws, size_t ws_size,
                              hipStream_t stream) {
    const float* input  = (const float*)d_in[0];
    const float* proto  = (const float*)d_in[1];
    const float* gumbel = (const float*)d_in[2];
    float* out = (float*)d_out;
    float* ws  = (float*)d_ws;

    ushort_t* Xh   = (ushort_t*)(out + OUT_PT);     // f16 x-hat in pt region
    ushort_t* Ph   = (ushort_t*)(ws + WS_PH);
    ushort_t* PTh  = (ushort_t*)(ws + WS_PTH);
    ushort_t* Eh   = (ushort_t*)(ws + WS_SIM);      // f16 E (softmax output)

    norm_p_kernel<<<K / 4, 256, 0, stream>>>(proto, out, ws, Ph);
    {
        dim3 grid(K / 64, D / 64);
        ptcvt_kernel<<<grid, 256, 0, stream>>>(out, PTh);
    }
    xcvt_kernel<<<B / 4, 256, 0, stream>>>(input, Xh);
    // fused sim-GEMM + gumbel-softmax: Eh = softmax((Xh·Ph^T + g)/tau)
    simsm_kernel<<<B / 32, 1024, 0, stream>>>(Xh, Ph, gumbel, Eh, ws);
    {
        // pt = Eh · PTh^T   (A: [B][1024] f16, B: [512][1024], C: [B][512] fp32)
        dim3 grid(D / 128, B / 128);
        gemm_bt2<1024, 1024, D, 1024, false><<<grid, 256, 0, stream>>>(Eh, PTh, out + OUT_PT);
    }
    finalize_kernel<<<1, 256, 0, stream>>>(out, ws);
}

// Round 6
// 216.100 us; speedup vs baseline: 1.1863x; 1.1863x over previous
//
#include <hip/hip_runtime.h>
#include <math.h>

// Problem constants
#define B  16384
#define K  1024
#define D  512
#define TAU_INV 10.0f
#define EPS 1e-12f

// softmax in base-2: log2(e^{(s+g)/tau}) = SM_C1*s - 10*log2(-log2(u)) + SM_C2
//   tau = 0.1 ; SM_C1 = 10*log2(e) ; SM_C2 = -10*log2(ln 2)
#define SM_C1 14.426950408889634f
#define SM_C2 5.287663729448977f

typedef unsigned short ushort_t;

// raw gfx950 transcendentals: v_log_f32 = log2(x), v_exp_f32 = 2^x
#define LOG2F(x) __builtin_amdgcn_logf(x)
#define EXP2F(x) __builtin_amdgcn_exp2f(x)

// d_out layout (floats): [0, B*D) pt ; [B*D, B*D+K*D) p ; then sim_loss, div_loss
#define OUT_PT   0
#define OUT_P    (B*D)
#define OUT_SIM  (B*D + K*D)
#define OUT_DIV  (B*D + K*D + 1)

// ws layout (floats):
//  [1024,2048)      softmax per-block dot partials (1024)
//  [32768, +B*K/2)  simh f16 [B][1024]; after softmax same bytes hold Eh f16
//  then Ph   [1024][512] f16 (1 MB)
//  then PTh  [512][1024] f16 (1 MB)
//  then DIAGP[256], COLP[256][512]  (norm_p per-block partials, no atomics)
#define WS_RED   1024
#define WS_SIM   32768
#define WS_PH    (WS_SIM + (B*K)/2)
#define WS_PTH   (WS_PH + (K*D)/2)
#define WS_DIAGP (WS_PTH + (K*D)/2)
#define WS_COLP  (WS_DIAGP + 256)

// Xh f16 [16384][512] (16 MB) lives in d_out's pt region, consumed by gemm1
// before gemm2 overwrites pt.

typedef _Float16 half8 __attribute__((ext_vector_type(8)));
typedef float f32x4 __attribute__((ext_vector_type(4)));

__device__ __forceinline__ float wave_reduce_sum(float v) {
    #pragma unroll
    for (int off = 32; off >= 1; off >>= 1) v += __shfl_down(v, off);
    return v;
}
__device__ __forceinline__ float wave_reduce_max(float v) {
    #pragma unroll
    for (int off = 32; off >= 1; off >>= 1) v = fmaxf(v, __shfl_down(v, off));
    return v;
}

__device__ __forceinline__ ushort_t f2h(float f) {
    _Float16 h = (_Float16)f;
    return __builtin_bit_cast(ushort_t, h);
}
__device__ __forceinline__ float h2f(ushort_t u) {
    return (float)__builtin_bit_cast(_Float16, u);
}

__device__ __forceinline__ void async16(const void* g, void* l) {
    __builtin_amdgcn_global_load_lds(
        (const __attribute__((address_space(1))) unsigned int*)g,
        (__attribute__((address_space(3))) unsigned int*)l, 16, 0, 0);
}

// Normalize prototypes (one wave per row, 4 rows/block). Fused outputs:
//  - phat fp32 -> d_out (output 1)
//  - Ph f16 [1024][512]
//  - per-block colsum partial [512] -> ws[WS_COLP + blk*512]
//  - per-block diag partial -> ws[WS_DIAGP + blk]
// No atomics anywhere.
__global__ __launch_bounds__(256) void norm_p_kernel(const float* __restrict__ proto,
                                                     float* __restrict__ out,
                                                     float* __restrict__ ws,
                                                     ushort_t* __restrict__ Ph) {
    __shared__ float cs[4][512];
    __shared__ float red[4];
    int tid = threadIdx.x, wid = tid >> 6, lane = tid & 63;
    int row = blockIdx.x * 4 + wid;
    const float4* pr = (const float4*)(proto + (size_t)row * D);
    float4 a = pr[lane * 2], b = pr[lane * 2 + 1];
    float ss = a.x*a.x + a.y*a.y + a.z*a.z + a.w*a.w
             + b.x*b.x + b.y*b.y + b.z*b.z + b.w*b.w;
    ss = wave_reduce_sum(ss);
    ss = __shfl(ss, 0);
    float inv = 1.0f / fmaxf(sqrtf(ss), EPS);
    float4 na = make_float4(a.x*inv, a.y*inv, a.z*inv, a.w*inv);
    float4 nb = make_float4(b.x*inv, b.y*inv, b.z*inv, b.w*inv);
    float4* po = (float4*)(out + OUT_P + (size_t)row * D);
    po[lane * 2]     = na;
    po[lane * 2 + 1] = nb;
    ushort4* ph = (ushort4*)(Ph + (size_t)row * D);
    ph[lane * 2]     = make_ushort4(f2h(na.x), f2h(na.y), f2h(na.z), f2h(na.w));
    ph[lane * 2 + 1] = make_ushort4(f2h(nb.x), f2h(nb.y), f2h(nb.z), f2h(nb.w));
    *(float4*)(&cs[wid][lane * 8])     = na;
    *(float4*)(&cs[wid][lane * 8 + 4]) = nb;
    if (lane == 0) red[wid] = ss * inv * inv;
    __syncthreads();
    float c0 = cs[0][tid] + cs[1][tid] + cs[2][tid] + cs[3][tid];
    float c1 = cs[0][tid + 256] + cs[1][tid + 256] + cs[2][tid + 256] + cs[3][tid + 256];
    ws[WS_COLP + (size_t)blockIdx.x * 512 + tid]       = c0;
    ws[WS_COLP + (size_t)blockIdx.x * 512 + tid + 256] = c1;
    if (tid == 0) ws[WS_DIAGP + blockIdx.x] = red[0] + red[1] + red[2] + red[3];
}

// PTh [512][1024] f16: transpose of phat
__global__ __launch_bounds__(256) void ptcvt_kernel(const float* __restrict__ out,
                                                    ushort_t* __restrict__ PT) {
    __shared__ float tile[64][65];
    int k0 = blockIdx.x * 64, d0 = blockIdx.y * 64;
    int tid = threadIdx.x;
    const float* phat = out + OUT_P;
    #pragma unroll
    for (int i = tid; i < 64 * 64; i += 256) {
        int kk = i >> 6, dd = i & 63;
        tile[dd][kk] = phat[(size_t)(k0 + kk) * D + d0 + dd];
    }
    __syncthreads();
    #pragma unroll
    for (int i = tid; i < 64 * 64; i += 256) {
        int dd = i >> 6, kk = i & 63;
        PT[(size_t)(d0 + dd) * K + k0 + kk] = f2h(tile[dd][kk]);
    }
}

// Fused x row-norm + f16 convert: Xh [16384][512] in out's pt region.
__global__ __launch_bounds__(256) void xcvt_kernel(const float* __restrict__ x,
                                                   ushort_t* __restrict__ Xh) {
    int wid = threadIdx.x >> 6, lane = threadIdx.x & 63;
    int row = blockIdx.x * 4 + wid;
    const float4* xr = (const float4*)(x + (size_t)row * D);
    float4 a = xr[lane * 2], b = xr[lane * 2 + 1];
    float ss = a.x*a.x + a.y*a.y + a.z*a.z + a.w*a.w
             + b.x*b.x + b.y*b.y + b.z*b.z + b.w*b.w;
    ss = wave_reduce_sum(ss);
    ss = __shfl(ss, 0);
    float inv = 1.0f / fmaxf(sqrtf(ss), EPS);
    ushort4 h0 = make_ushort4(f2h(a.x*inv), f2h(a.y*inv), f2h(a.z*inv), f2h(a.w*inv));
    ushort4 h1 = make_ushort4(f2h(b.x*inv), f2h(b.y*inv), f2h(b.z*inv), f2h(b.w*inv));
    ushort4* xo = (ushort4*)(Xh + (size_t)row * D);
    xo[lane * 2]     = h0;
    xo[lane * 2 + 1] = h1;
}

// f16 bt-GEMM, BK=64 via TWO independent 32-k panels (m97 recipe per panel):
// 128x128 block tile, 4 waves (2x2), 4x4 16x16x32-f16 MFMA tiles per wave per
// panel -> 32 MFMA per barrier pair. global_load_lds width-16 staging.
// F16C: write C as f16 (for simh), else fp32.
template<int LDA, int LDB, int LDC, int KK, bool F16C>
__global__ __launch_bounds__(256) void gemm_bt2(const ushort_t* __restrict__ A,
                                                const ushort_t* __restrict__ Bm,
                                                void* __restrict__ Cv) {
    __shared__ __align__(16) ushort_t As[2 * 128 * 32];
    __shared__ __align__(16) ushort_t Bs[2 * 128 * 32];
    int tid = threadIdx.x;
    int wid = tid >> 6, lane = tid & 63;
    int quad = lane >> 4, l16 = lane & 15;
    int wm = (wid & 1) * 64, wn = (wid >> 1) * 64;
    int bn0 = blockIdx.x * 128, bm0 = blockIdx.y * 128;
    int ldrow = lane >> 2;           // 0..15
    int lcol  = (lane & 3) * 8;      // halves within a 32-half panel row

    f32x4 acc[4][4] = {};

    // wave-uniform LDS staging bases: panel p, row-group q
    ushort_t* AsD[2][2] = {
        { As + (wid * 16) * 32,        As + (64 + wid * 16) * 32 },
        { As + 4096 + (wid * 16) * 32, As + 4096 + (64 + wid * 16) * 32 } };
    ushort_t* BsD[2][2] = {
        { Bs + (wid * 16) * 32,        Bs + (64 + wid * 16) * 32 },
        { Bs + 4096 + (wid * 16) * 32, Bs + 4096 + (64 + wid * 16) * 32 } };

    const ushort_t* Ab = A + (size_t)(bm0 + wid * 16 + ldrow) * LDA + lcol;
    const ushort_t* Bb = Bm + (size_t)(bn0 + wid * 16 + ldrow) * LDB + lcol;

    for (int kc = 0; kc < KK; kc += 64) {
        async16(Ab + kc,                       AsD[0][0]);
        async16(Ab + kc + (size_t)64 * LDA,    AsD[0][1]);
        async16(Ab + kc + 32,                  AsD[1][0]);
        async16(Ab + kc + 32 + (size_t)64*LDA, AsD[1][1]);
        async16(Bb + kc,                       BsD[0][0]);
        async16(Bb + kc + (size_t)64 * LDB,    BsD[0][1]);
        async16(Bb + kc + 32,                  BsD[1][0]);
        async16(Bb + kc + 32 + (size_t)64*LDB, BsD[1][1]);
        __syncthreads();
        #pragma unroll
        for (int p = 0; p < 2; ++p) {
            half8 af[4], bg[4];
            #pragma unroll
            for (int i = 0; i < 4; ++i)
                af[i] = *(const half8*)(As + p * 4096 + (wm + 16 * i + l16) * 32 + quad * 8);
            #pragma unroll
            for (int j = 0; j < 4; ++j)
                bg[j] = *(const half8*)(Bs + p * 4096 + (wn + 16 * j + l16) * 32 + quad * 8);
            #pragma unroll
            for (int i = 0; i < 4; ++i)
                #pragma unroll
                for (int j = 0; j < 4; ++j)
                    acc[i][j] = __builtin_amdgcn_mfma_f32_16x16x32_f16(af[i], bg[j], acc[i][j], 0, 0, 0);
        }
        __syncthreads();
    }
    #pragma unroll
    for (int i = 0; i < 4; ++i) {
        #pragma unroll
        for (int j = 0; j < 4; ++j) {
            #pragma unroll
            for (int r = 0; r < 4; ++r) {
                int row = bm0 + wm + 16 * i + quad * 4 + r;
                int col = bn0 + wn + 16 * j + l16;
                if (F16C)
                    ((ushort_t*)Cv)[(size_t)row * LDC + col] = f2h(acc[i][j][r]);
                else
                    ((float*)Cv)[(size_t)row * LDC + col] = acc[i][j][r];
            }
        }
    }
}

// Row softmax with gumbel, base-2 domain (2x v_log + 1x v_exp per element
// instead of 2x libm logf + expf). One WAVE per row, 4 rows/wave. Reads simh
// f16, writes Eh f16 in-place. Per-block dot partial (no contended atomics).
__global__ __launch_bounds__(256) void softmax_rows(const float* __restrict__ u,
                                                    float* __restrict__ ws) {
    ushort_t* simh = (ushort_t*)(ws + WS_SIM);
    int tid = threadIdx.x;
    int wid = tid >> 6, lane = tid & 63;
    int gw = blockIdx.x * 4 + wid;        // 0..4095
    float dotacc = 0.0f;

    for (int r = 0; r < 4; ++r) {
        int row = gw + 4096 * r;
        ushort4* srow = (ushort4*)(simh + (size_t)row * K);
        const float4* urow = (const float4*)(u + (size_t)row * K);
        float4 s[4], z[4];
        #pragma unroll
        for (int j = 0; j < 4; ++j) {
            ushort4 sh = srow[lane + 64 * j];
            float4 uu = urow[lane + 64 * j];
            s[j] = make_float4(h2f(sh.x), h2f(sh.y), h2f(sh.z), h2f(sh.w));
            z[j].x = SM_C1 * s[j].x - 10.0f * LOG2F(-LOG2F(uu.x)) + SM_C2;
            z[j].y = SM_C1 * s[j].y - 10.0f * LOG2F(-LOG2F(uu.y)) + SM_C2;
            z[j].z = SM_C1 * s[j].z - 10.0f * LOG2F(-LOG2F(uu.z)) + SM_C2;
            z[j].w = SM_C1 * s[j].w - 10.0f * LOG2F(-LOG2F(uu.w)) + SM_C2;
        }
        float m = z[0].x;
        #pragma unroll
        for (int j = 0; j < 4; ++j)
            m = fmaxf(m, fmaxf(fmaxf(z[j].x, z[j].y), fmaxf(z[j].z, z[j].w)));
        m = wave_reduce_max(m);
        m = __shfl(m, 0);

        float4 e[4];
        float l = 0.0f;
        #pragma unroll
        for (int j = 0; j < 4; ++j) {
            e[j].x = EXP2F(z[j].x - m);
            e[j].y = EXP2F(z[j].y - m);
            e[j].z = EXP2F(z[j].z - m);
            e[j].w = EXP2F(z[j].w - m);
            l += e[j].x + e[j].y + e[j].z + e[j].w;
        }
        l = wave_reduce_sum(l);
        l = __shfl(l, 0);
        float inv = 1.0f / l;

        #pragma unroll
        for (int j = 0; j < 4; ++j) {
            float ex = e[j].x * inv, ey = e[j].y * inv,
                  ez = e[j].z * inv, ew = e[j].w * inv;
            srow[lane + 64 * j] = make_ushort4(f2h(ex), f2h(ey), f2h(ez), f2h(ew));
            dotacc += ex * s[j].x + ey * s[j].y + ez * s[j].z + ew * s[j].w;
        }
    }

    dotacc = wave_reduce_sum(dotacc);
    __shared__ float red[4];
    if (lane == 0) red[wid] = dotacc;
    __syncthreads();
    if (tid == 0) ws[WS_RED + blockIdx.x] = red[0] + red[1] + red[2] + red[3];
}

// Final reduction, 1024 threads (serial depth 128 instead of 256, full
// coalescing, 16 waves): softmax dot partials (1024), diag partials
// (256), colsum partials (256 x 512 -> ||colsum||^2).
__global__ __launch_bounds__(1024) void finalize_kernel(float* __restrict__ out,
                                                        const float* __restrict__ ws) {
    __shared__ float cred[1024];
    __shared__ float rd[16], rs[16], rg[16];
    int tid = threadIdx.x, wid = tid >> 6, lane = tid & 63;
    int col = tid & 511, h = tid >> 9;    // h=0: b2 0..127, h=1: b2 128..255
    float c = 0.0f;
    #pragma unroll 8
    for (int b2 = h * 128; b2 < h * 128 + 128; ++b2)
        c += ws[WS_COLP + (size_t)b2 * 512 + col];
    cred[tid] = c;
    float vdot = ws[WS_RED + tid];
    float diag = (tid < 256) ? ws[WS_DIAGP + tid] : 0.0f;
    __syncthreads();
    float vssq = 0.0f;
    if (tid < 512) {
        float cc = cred[tid] + cred[tid + 512];
        vssq = cc * cc;
    }
    vdot = wave_reduce_sum(vdot);
    vssq = wave_reduce_sum(vssq);
    diag = wave_reduce_sum(diag);
    if (lane == 0) { rd[wid] = vdot; rs[wid] = vssq; rg[wid] = diag; }
    __syncthreads();
    if (tid == 0) {
        float dot = 0.0f, ssq = 0.0f, dg = 0.0f;
        #pragma unroll
        for (int w = 0; w < 16; ++w) { dot += rd[w]; ssq += rs[w]; dg += rg[w]; }
        out[OUT_SIM] = 1.0f - dot * (1.0f / (float)B);
        out[OUT_DIV] = ssq - dg;
    }
}

extern "C" void kernel_launch(void* const* d_in, const int* in_sizes, int n_in,
                              void* d_out, int out_size, void* d_ws, size_t ws_size,
                              hipStream_t stream) {
    const float* input  = (const float*)d_in[0];
    const float* proto  = (const float*)d_in[1];
    const float* gumbel = (const float*)d_in[2];
    float* out = (float*)d_out;
    float* ws  = (float*)d_ws;

    ushort_t* Xh   = (ushort_t*)(out + OUT_PT);     // f16 x-hat in pt region
    ushort_t* Ph   = (ushort_t*)(ws + WS_PH);
    ushort_t* PTh  = (ushort_t*)(ws + WS_PTH);
    ushort_t* simh = (ushort_t*)(ws + WS_SIM);      // f16 sim, then Eh in-place

    norm_p_kernel<<<K / 4, 256, 0, stream>>>(proto, out, ws, Ph);
    {
        dim3 grid(K / 64, D / 64);
        ptcvt_kernel<<<grid, 256, 0, stream>>>(out, PTh);
    }
    xcvt_kernel<<<B / 4, 256, 0, stream>>>(input, Xh);
    {
        // simh = Xh · Ph^T   (A: [B][512], B: [K][512], C: [B][K] f16)
        dim3 grid(K / 128, B / 128);
        gemm_bt2<512, 512, K, 512, true><<<grid, 256, 0, stream>>>(Xh, Ph, simh);
    }
    softmax_rows<<<1024, 256, 0, stream>>>(gumbel, ws);
    {
        // pt = Eh · PTh^T   (A: [B][1024] f16, B: [512][1024], C: [B][512] fp32)
        dim3 grid(D / 128, B / 128);
        gemm_bt2<1024, 1024, D, 1024, false><<<grid, 256, 0, stream>>>(simh, PTh, out + OUT_PT);
    }
    finalize_kernel<<<1, 1024, 0, stream>>>(out, ws);
}